// Round 6
// baseline (611.885 us; speedup 1.0000x reference)
//
#include <hip/hip_runtime.h>
#include <cstddef>

// SkipGRU on MI355X (gfx950) — round 6.
// Delta vs round 5: the K-loop no longer touches LDS at all. The packed
// layouts (granule = [64 rows][8 bf16] in exact MFMA lane order) let each wave
// global_load_dwordx4 its A/B fragments straight from L2 into registers
// (16-lane groups read 256B contiguous lines). No staging, no ds_read, NO
// __syncthreads in the K-loop -> compiler pipelines loads across chunks.
// Manual 1-chunk software prefetch keeps ~8 loads in flight per wave.
// LDS is used only by the 9KB epilogue transpose.
//
// Layouts (unchanged):
//  xb[t][nb(64)][kt(16)][g(4)][row(64)][8] bf16 granules (16B).
//  Bt[cc(24)][kt(32)][g(4)][col(64)][8]    (cc = 64 gemm-cols).
//  h ping-pong: same granule layout as xb per nb.

typedef unsigned short u16;
typedef __attribute__((ext_vector_type(8))) short short8;
typedef __attribute__((ext_vector_type(8))) u16 u16x8;
typedef __attribute__((ext_vector_type(4))) float floatx4;

#define MFMA16(a, b, c) __builtin_amdgcn_mfma_f32_16x16x32_bf16((a), (b), (c), 0, 0, 0)

__device__ __forceinline__ u16 f32_to_bf16(float f) {
  union { float f; unsigned int u; } c; c.f = f;
  unsigned int u = c.u + 0x7FFFu + ((c.u >> 16) & 1u);  // RNE
  return (u16)(u >> 16);
}
__device__ __forceinline__ float bf16_to_f32(u16 v) {
  union { unsigned int u; float f; } c; c.u = ((unsigned int)v) << 16;
  return c.f;
}
__device__ __forceinline__ float sigmoidf_(float x) {
  return 1.0f / (1.0f + __expf(-x));
}

// ---------------------------------------------------------------------------
// pack_x: coalesced. Block = one (t, nb): 64 rows x 512 c. (round-5 version)
// ---------------------------------------------------------------------------
__global__ __launch_bounds__(256)
void pack_x(const float* __restrict__ x, u16* __restrict__ xb) {
  __shared__ u16 sm[64 * 512];              // 64KB
  const int t = blockIdx.x >> 6;
  const int nb = blockIdx.x & 63;
  const int tid = threadIdx.x;
#pragma unroll
  for (int it = 0; it < 16; ++it) {
    int idx = it * 256 + tid;
    int row = idx >> 6, ch = idx & 63;      // row 0..63, ch = 8-float chunk
    int xrow = (nb * 2 + (row >> 5)) * 512 + t * 32 + (row & 31);
    const float* src = x + (size_t)xrow * 512 + ch * 8;
    floatx4 va = *(const floatx4*)src;
    floatx4 vb = *(const floatx4*)(src + 4);
    u16x8 pk;
    pk[0] = f32_to_bf16(va[0]); pk[1] = f32_to_bf16(va[1]);
    pk[2] = f32_to_bf16(va[2]); pk[3] = f32_to_bf16(va[3]);
    pk[4] = f32_to_bf16(vb[0]); pk[5] = f32_to_bf16(vb[1]);
    pk[6] = f32_to_bf16(vb[2]); pk[7] = f32_to_bf16(vb[3]);
    *(u16x8*)&sm[row * 512 + (ch ^ (row & 7)) * 8] = pk;
  }
  __syncthreads();
  u16* dst = xb + (size_t)blockIdx.x * 32768;   // blockIdx = t*64+nb = layout order
#pragma unroll
  for (int it = 0; it < 16; ++it) {
    int idx = it * 256 + tid;
    int row = idx & 63, g = (idx >> 6) & 3, kt = idx >> 8;
    int ch = kt * 4 + g;
    u16x8 vv = *(const u16x8*)&sm[row * 512 + (ch ^ (row & 7)) * 8];
    *(u16x8*)(dst + (size_t)idx * 8) = vv;
  }
}

// ---------------------------------------------------------------------------
// pack_Bt: [W;U] -> Bt bf16 [cc(24)][kt(32)][g(4)][col(64)][8]
// ---------------------------------------------------------------------------
__global__ void pack_Bt(const float* __restrict__ W, const float* __restrict__ U,
                        u16* __restrict__ Bt) {
  size_t gid = (size_t)blockIdx.x * 256 + threadIdx.x;   // < 196608
  int col = (int)(gid & 63);
  int g   = (int)((gid >> 6) & 3);
  int kt  = (int)((gid >> 8) & 31);
  int cc  = (int)(gid >> 13);
  int c = cc * 64 + col;
  int k0 = kt * 32 + g * 8;
  u16x8 pk;
#pragma unroll
  for (int j = 0; j < 8; ++j) {
    int k = k0 + j;
    float v = (k < 512) ? W[(size_t)k * 1536 + c] : U[(size_t)(k - 512) * 1536 + c];
    pk[j] = f32_to_bf16(v);
  }
  *(u16x8*)(Bt + gid * 8) = pk;
}

// ---------------------------------------------------------------------------
// gru_step: one GRU timestep, register-direct fragments (no K-loop LDS).
// Grid 512 linear, XCD-swizzled: nb = (idx>>6)*8 + (idx&7), hb = (idx>>3)&7.
// Block tile 64n x 192c; 4 waves (wy,wx); wave = 32n x (3 gates x 32 h-cols).
// ---------------------------------------------------------------------------
__global__ __launch_bounds__(256)
void gru_step(const u16* __restrict__ xb, const u16* __restrict__ Bt,
              const float* __restrict__ bias,
              const u16* __restrict__ h_in, u16* __restrict__ h_out,
              float* __restrict__ out, int t, int first, int last) {
  __shared__ alignas(16) u16 Ct[64 * 72];         // epilogue only (9KB)
  const int tid = threadIdx.x;
  const int idx = blockIdx.x;
  const int nb = ((idx >> 6) << 3) | (idx & 7);   // 0..63
  const int hb = (idx >> 3) & 7;                  // 0..7
  const int lane = tid & 63;
  const int wy = (tid >> 7) & 1, wx = (tid >> 6) & 1;
  const int q = lane >> 4, lc = lane & 15;

  // Fragment offsets within a 2048-u16 (4KB) panel, in u16 units.
  const int aoff = (q * 64 + wy * 32 + lc) * 8;   // a1 = +128
  const int boff = (q * 64 + wx * 32 + lc) * 8;   // ci=1 -> +128

  const u16* pAx = xb + (size_t)(t * 64 + nb) * 32768 + aoff;
  const u16* pAh = h_in + (size_t)nb * 32768 + aoff;
  const u16* pBz = Bt + (size_t)(hb +  0) * 65536 + boff;   // cc = hb
  const u16* pBr = Bt + (size_t)(hb +  8) * 65536 + boff;   // cc = 8+hb
  const u16* pBh = Bt + (size_t)(hb + 16) * 65536 + boff;   // cc = 16+hb

  floatx4 acZ[2][2] = {{{0.f,0.f,0.f,0.f},{0.f,0.f,0.f,0.f}},{{0.f,0.f,0.f,0.f},{0.f,0.f,0.f,0.f}}};
  floatx4 acR[2][2] = {{{0.f,0.f,0.f,0.f},{0.f,0.f,0.f,0.f}},{{0.f,0.f,0.f,0.f},{0.f,0.f,0.f,0.f}}};
  floatx4 acX[2][2] = {{{0.f,0.f,0.f,0.f},{0.f,0.f,0.f,0.f}},{{0.f,0.f,0.f,0.f},{0.f,0.f,0.f,0.f}}};
  floatx4 acH[2][2] = {{{0.f,0.f,0.f,0.f},{0.f,0.f,0.f,0.f}},{{0.f,0.f,0.f,0.f},{0.f,0.f,0.f,0.f}}};

  const int nch = first ? 16 : 32;

  // Software pipeline: fragments for chunk kt loaded while chunk kt-1 computes.
  short8 a0, a1, bz0, bz1, br0, br1, bh0, bh1;
  auto loadf = [&](int kt) {
    const u16* pa = (kt < 16) ? (pAx + (size_t)kt * 2048)
                              : (pAh + (size_t)(kt - 16) * 2048);
    const size_t bo = (size_t)kt * 2048;
    a0  = *(const short8*)(pa);
    a1  = *(const short8*)(pa + 128);
    bz0 = *(const short8*)(pBz + bo);
    bz1 = *(const short8*)(pBz + bo + 128);
    br0 = *(const short8*)(pBr + bo);
    br1 = *(const short8*)(pBr + bo + 128);
    bh0 = *(const short8*)(pBh + bo);
    bh1 = *(const short8*)(pBh + bo + 128);
  };

  loadf(0);
  for (int kt = 0; kt < nch; ++kt) {
    short8 ca0 = a0, ca1 = a1, cz0 = bz0, cz1 = bz1;
    short8 cr0 = br0, cr1 = br1, ch0 = bh0, ch1 = bh1;
    if (kt + 1 < nch) loadf(kt + 1);
    floatx4 (&acT)[2][2] = (kt < 16) ? acX : acH;   // 3rd gate: x@W -> acX, h@U -> acH
    acZ[0][0] = MFMA16(ca0, cz0, acZ[0][0]);
    acZ[1][0] = MFMA16(ca1, cz0, acZ[1][0]);
    acZ[0][1] = MFMA16(ca0, cz1, acZ[0][1]);
    acZ[1][1] = MFMA16(ca1, cz1, acZ[1][1]);
    acR[0][0] = MFMA16(ca0, cr0, acR[0][0]);
    acR[1][0] = MFMA16(ca1, cr0, acR[1][0]);
    acR[0][1] = MFMA16(ca0, cr1, acR[0][1]);
    acR[1][1] = MFMA16(ca1, cr1, acR[1][1]);
    acT[0][0] = MFMA16(ca0, ch0, acT[0][0]);
    acT[1][0] = MFMA16(ca1, ch0, acT[1][0]);
    acT[0][1] = MFMA16(ca0, ch1, acT[0][1]);
    acT[1][1] = MFMA16(ca1, ch1, acT[1][1]);
  }

  // ---- Epilogue. C/D layout: col = lane&15, row = quad*4 + reg ----
  const float* b0 = bias;
  const float* b1 = bias + 1536;
#pragma unroll
  for (int ci = 0; ci < 2; ++ci) {
    const int hcl = wx * 32 + ci * 16 + lc;    // 0..63
    const int hg = hb * 64 + hcl;              // 0..511
    const float bz = b0[hg] + b1[hg];
    const float br = b0[512 + hg] + b1[512 + hg];
    const float b0h = b0[1024 + hg];
    const float b1h = b1[1024 + hg];
    const int ktg = hg >> 5;
    const int gg = (hg >> 3) & 3;
    const size_t hbase = (((size_t)nb * 16 + ktg) * 4 + gg) * 64;
#pragma unroll
    for (int mi = 0; mi < 2; ++mi) {
#pragma unroll
      for (int reg = 0; reg < 4; ++reg) {
        const int nl = wy * 32 + mi * 16 + q * 4 + reg;   // 0..63
        const int n = nb * 64 + nl;
        float z = sigmoidf_(acZ[mi][ci][reg] + bz);
        float r = sigmoidf_(acR[mi][ci][reg] + br);
        float hh = acX[mi][ci][reg] + b0h + r * (acH[mi][ci][reg] + b1h);
        hh = fmaxf(hh, 0.0f);
        float hp = 0.0f;
        if (!first) hp = bf16_to_f32(h_in[(hbase + nl) * 8 + (hg & 7)]);
        float v = z * hp + (1.0f - z) * hh;
        if (last) out[(size_t)n * 512 + hg] = v;
        else      Ct[nl * 72 + hcl] = f32_to_bf16(v);
      }
    }
  }
  if (!last) {
    __syncthreads();
    // Re-emit h in granule layout: 512 granules (row64 x g4 x ktl2), 2/thread.
#pragma unroll
    for (int i = 0; i < 2; ++i) {
      int e = i * 256 + tid;
      int row = e & 63;
      int g = (e >> 6) & 3;
      int ktl = e >> 8;                         // 0..1
      u16x8 vv = *(const u16x8*)(Ct + row * 72 + ktl * 32 + g * 8);
      *(u16x8*)(h_out + ((((size_t)nb * 16 + (hb * 2 + ktl)) * 4 + g) * 64 + row) * 8) = vv;
    }
  }
}

// ---------------------------------------------------------------------------
extern "C" void kernel_launch(void* const* d_in, const int* in_sizes, int n_in,
                              void* d_out, int out_size, void* d_ws, size_t ws_size,
                              hipStream_t stream) {
  const float* x = (const float*)d_in[0];    // (128,512,512)
  const float* W = (const float*)d_in[1];    // (512,1536)
  const float* U = (const float*)d_in[2];    // (512,1536)
  const float* bias = (const float*)d_in[3]; // (2,1536)
  float* out = (float*)d_out;                // (128,16384)

  u16* xb = (u16*)d_ws;                      // 16*64*32768 u16 = 64 MB
  u16* Bt = xb + (size_t)16 * 64 * 32768;    // 3 MB
  u16* h0 = Bt + (size_t)1536 * 1024;        // 4 MB
  u16* h1 = h0 + (size_t)4096 * 512;         // 4 MB

  pack_x<<<1024, 256, 0, stream>>>(x, xb);
  pack_Bt<<<768, 256, 0, stream>>>(W, U, Bt);

  for (int t = 0; t < 16; ++t) {
    const u16* hin = (t & 1) ? h1 : h0;      // t=0 never reads h
    u16* hout = (t & 1) ? h0 : h1;
    gru_step<<<512, 256, 0, stream>>>(
        xb, Bt, bias, hin, hout, out, t, (t == 0) ? 1 : 0, (t == 15) ? 1 : 0);
  }
}